// Round 2
// baseline (55.307 us; speedup 1.0000x reference)
//
#include <hip/hip_runtime.h>

// SeqMasking: right-align kept tokens (rand > 0.15), zero-fill left prefix.
// B=64, T=2048, D=256, fp32.
//
// ws layout: int l[B]      at offset 0
//            int src[B][T] at offset 256 bytes

#define P_DROP 0.15f

typedef float f32x4 __attribute__((ext_vector_type(4)));

__global__ __launch_bounds__(256)
void seqmask_scan_kernel(const float* __restrict__ rand,
                         int* __restrict__ l_out,
                         int* __restrict__ src,
                         int T) {
    const int b    = blockIdx.x;
    const int tid  = threadIdx.x;
    const int wave = tid >> 6;
    const int lane = tid & 63;
    const float* r = rand + (size_t)b * T + tid * 8;

    // vectorized rand load: 8 floats as 2x float4
    f32x4 r0 = *reinterpret_cast<const f32x4*>(r);
    f32x4 r1 = *reinterpret_cast<const f32x4*>(r + 4);

    int keep[8];
    keep[0] = r0.x > P_DROP; keep[1] = r0.y > P_DROP;
    keep[2] = r0.z > P_DROP; keep[3] = r0.w > P_DROP;
    keep[4] = r1.x > P_DROP; keep[5] = r1.y > P_DROP;
    keep[6] = r1.z > P_DROP; keep[7] = r1.w > P_DROP;

    int cnt = 0;
#pragma unroll
    for (int i = 0; i < 8; ++i) cnt += keep[i];

    // wave-level inclusive scan (no barriers)
    int inc = cnt;
#pragma unroll
    for (int off = 1; off < 64; off <<= 1) {
        int n = __shfl_up(inc, off, 64);
        if (lane >= off) inc += n;
    }

    __shared__ int wsum[4];
    if (lane == 63) wsum[wave] = inc;
    __syncthreads();

    int wexcl = 0;
#pragma unroll
    for (int w = 0; w < 4; ++w) wexcl += (w < wave) ? wsum[w] : 0;
    const int total = wsum[0] + wsum[1] + wsum[2] + wsum[3];
    if (tid == 0) l_out[b] = total;

    int pos = wexcl + inc - cnt;           // exclusive prefix for this thread
    int* sb = src + (size_t)b * T;
#pragma unroll
    for (int i = 0; i < 8; ++i) {
        if (keep[i]) {
            sb[pos] = tid * 8 + i;
            ++pos;
        }
    }
}

__global__ __launch_bounds__(256)
void seqmask_gather_kernel(const float* __restrict__ x,
                           const int* __restrict__ l_arr,
                           const int* __restrict__ src,
                           float* __restrict__ out,
                           int T, int D) {
    // One wave (64 lanes) per output row; 4 rows per block.
    const int row  = blockIdx.x * 4 + (threadIdx.x >> 6);
    const int lane = threadIdx.x & 63;
    const int b    = row >> 11;            // T = 2048
    const int j    = row & (T - 1);

    const int l = l_arr[b];                // wave-uniform -> scalar load
    const int q = j - (T - l);

    f32x4 v = (f32x4)(0.f, 0.f, 0.f, 0.f);
    if (q >= 0) {
        const int st = src[(size_t)b * T + q];
        v = __builtin_nontemporal_load(
                reinterpret_cast<const f32x4*>(
                    x + ((size_t)b * T + st) * D + lane * 4));
    }
    __builtin_nontemporal_store(
        v, reinterpret_cast<f32x4*>(out + (size_t)row * D + lane * 4));
}

extern "C" void kernel_launch(void* const* d_in, const int* in_sizes, int n_in,
                              void* d_out, int out_size, void* d_ws, size_t ws_size,
                              hipStream_t stream) {
    const float* x    = (const float*)d_in[0];   // (B, T, D) fp32
    const float* rand = (const float*)d_in[1];   // (B, T)    fp32
    float* out        = (float*)d_out;

    const int T  = 2048;
    const int BT = in_sizes[1];                  // B*T
    const int D  = in_sizes[0] / BT;             // 256

    int* l_arr = (int*)d_ws;
    int* src   = (int*)((char*)d_ws + 256);

    seqmask_scan_kernel<<<BT / T, 256, 0, stream>>>(rand, l_arr, src, T);
    seqmask_gather_kernel<<<BT / 4, 256, 0, stream>>>(x, l_arr, src, out, T, D);
}

// Round 3
// 45.960 us; speedup vs baseline: 1.2034x; 1.2034x over previous
//
#include <hip/hip_runtime.h>

// SeqMasking: right-align kept tokens (rand > 0.15), zero-fill left prefix.
// B=64, T=2048, D=256, fp32.
//
// ws layout: int l[B]      at offset 0
//            int src[B][T] at offset 256 bytes
//
// R2 lesson: __builtin_nontemporal_load/store on the gather stream cost +10us
// (45.6 -> 55.3). Plain loads/stores here; do not re-add nt hints.

#define P_DROP 0.15f

typedef float f32x4 __attribute__((ext_vector_type(4)));

__global__ __launch_bounds__(256)
void seqmask_scan_kernel(const float* __restrict__ rand,
                         int* __restrict__ l_out,
                         int* __restrict__ src,
                         int T) {
    const int b    = blockIdx.x;
    const int tid  = threadIdx.x;
    const int wave = tid >> 6;
    const int lane = tid & 63;
    const float* r = rand + (size_t)b * T + tid * 8;

    // vectorized rand load: 8 floats as 2x float4
    f32x4 r0 = *reinterpret_cast<const f32x4*>(r);
    f32x4 r1 = *reinterpret_cast<const f32x4*>(r + 4);

    int keep[8];
    keep[0] = r0.x > P_DROP; keep[1] = r0.y > P_DROP;
    keep[2] = r0.z > P_DROP; keep[3] = r0.w > P_DROP;
    keep[4] = r1.x > P_DROP; keep[5] = r1.y > P_DROP;
    keep[6] = r1.z > P_DROP; keep[7] = r1.w > P_DROP;

    int cnt = 0;
#pragma unroll
    for (int i = 0; i < 8; ++i) cnt += keep[i];

    // wave-level inclusive scan (no barriers)
    int inc = cnt;
#pragma unroll
    for (int off = 1; off < 64; off <<= 1) {
        int n = __shfl_up(inc, off, 64);
        if (lane >= off) inc += n;
    }

    __shared__ int wsum[4];
    if (lane == 63) wsum[wave] = inc;
    __syncthreads();

    int wexcl = 0;
#pragma unroll
    for (int w = 0; w < 4; ++w) wexcl += (w < wave) ? wsum[w] : 0;
    const int total = wsum[0] + wsum[1] + wsum[2] + wsum[3];
    if (tid == 0) l_out[b] = total;

    int pos = wexcl + inc - cnt;           // exclusive prefix for this thread
    int* sb = src + (size_t)b * T;
#pragma unroll
    for (int i = 0; i < 8; ++i) {
        if (keep[i]) {
            sb[pos] = tid * 8 + i;
            ++pos;
        }
    }
}

__global__ __launch_bounds__(256)
void seqmask_gather_kernel(const float* __restrict__ x,
                           const int* __restrict__ l_arr,
                           const int* __restrict__ src,
                           float* __restrict__ out,
                           int T, int D) {
    // One wave (64 lanes) per output row; 4 rows per block.
    const int row  = blockIdx.x * 4 + (threadIdx.x >> 6);
    const int lane = threadIdx.x & 63;
    const int b    = row >> 11;            // T = 2048
    const int j    = row & (T - 1);

    const int l = l_arr[b];                // wave-uniform -> scalar load
    const int q = j - (T - l);

    f32x4 v = (f32x4)(0.f, 0.f, 0.f, 0.f);
    if (q >= 0) {
        const int st = src[(size_t)b * T + q];
        v = *reinterpret_cast<const f32x4*>(
                x + ((size_t)b * T + st) * D + lane * 4);
    }
    *reinterpret_cast<f32x4*>(out + (size_t)row * D + lane * 4) = v;
}

extern "C" void kernel_launch(void* const* d_in, const int* in_sizes, int n_in,
                              void* d_out, int out_size, void* d_ws, size_t ws_size,
                              hipStream_t stream) {
    const float* x    = (const float*)d_in[0];   // (B, T, D) fp32
    const float* rand = (const float*)d_in[1];   // (B, T)    fp32
    float* out        = (float*)d_out;

    const int T  = 2048;
    const int BT = in_sizes[1];                  // B*T
    const int D  = in_sizes[0] / BT;             // 256

    int* l_arr = (int*)d_ws;
    int* src   = (int*)((char*)d_ws + 256);

    seqmask_scan_kernel<<<BT / T, 256, 0, stream>>>(rand, l_arr, src, T);
    seqmask_gather_kernel<<<BT / 4, 256, 0, stream>>>(x, l_arr, src, out, T, D);
}

// Round 4
// 42.903 us; speedup vs baseline: 1.2891x; 1.0713x over previous
//
#include <hip/hip_runtime.h>

// SeqMasking: right-align kept tokens (rand > 0.15), zero-fill left prefix.
// B=64, T=2048, D=256, fp32.
//
// R4: single fused kernel. Each 256-thread block owns 16 consecutive output
// rows of one batch and REDUNDANTLY recomputes that batch's keep-scan into an
// LDS compaction map (smap[2048], 8 KB), then gathers its rows. 128 blocks
// share each rand row -> re-reads are L2 hits. No inter-block communication,
// no scan kernel, no dependency gap.
//
// R2 lesson: __builtin_nontemporal_load/store cost +10us (45.6 -> 55.3).
// Plain loads/stores only.

#define P_DROP 0.15f

typedef float f32x4 __attribute__((ext_vector_type(4)));

__global__ __launch_bounds__(256)
void seqmask_fused_kernel(const float* __restrict__ x,
                          const float* __restrict__ rand,
                          float* __restrict__ out) {
    const int T = 2048, D = 256;
    const int b    = blockIdx.x >> 7;          // 128 blocks per batch
    const int j0   = (blockIdx.x & 127) << 4;  // 16 rows per block
    const int tid  = threadIdx.x;
    const int wave = tid >> 6;
    const int lane = tid & 63;

    __shared__ int smap[2048];   // compaction map: smap[k] = orig idx of k-th kept
    __shared__ int wsum[4];

    // ---- Phase 1: scan this batch's rand row (8 elems/thread, vectorized) ----
    const float* r = rand + (size_t)b * T + tid * 8;
    f32x4 r0 = *reinterpret_cast<const f32x4*>(r);
    f32x4 r1 = *reinterpret_cast<const f32x4*>(r + 4);

    int keep[8];
    keep[0] = r0.x > P_DROP; keep[1] = r0.y > P_DROP;
    keep[2] = r0.z > P_DROP; keep[3] = r0.w > P_DROP;
    keep[4] = r1.x > P_DROP; keep[5] = r1.y > P_DROP;
    keep[6] = r1.z > P_DROP; keep[7] = r1.w > P_DROP;

    int cnt = 0;
#pragma unroll
    for (int i = 0; i < 8; ++i) cnt += keep[i];

    int inc = cnt;                             // wave inclusive scan, no barrier
#pragma unroll
    for (int off = 1; off < 64; off <<= 1) {
        int n = __shfl_up(inc, off, 64);
        if (lane >= off) inc += n;
    }
    if (lane == 63) wsum[wave] = inc;
    __syncthreads();

    int wexcl = 0;
#pragma unroll
    for (int w = 0; w < 4; ++w) wexcl += (w < wave) ? wsum[w] : 0;
    const int l = wsum[0] + wsum[1] + wsum[2] + wsum[3];

    int pos = wexcl + inc - cnt;               // exclusive prefix for this thread
#pragma unroll
    for (int i = 0; i < 8; ++i) {
        if (keep[i]) smap[pos++] = tid * 8 + i;
    }
    __syncthreads();

    // ---- Phase 2: gather 16 rows (4 per wave), 1 KB per row ----
    const size_t xb = (size_t)b * T * D;
#pragma unroll
    for (int rr = 0; rr < 4; ++rr) {
        const int j = j0 + wave * 4 + rr;
        const int q = j - (T - l);
        f32x4 v = (f32x4)(0.f, 0.f, 0.f, 0.f);
        if (q >= 0) {
            const int st = smap[q];            // wave-uniform LDS broadcast
            v = *reinterpret_cast<const f32x4*>(x + xb + (size_t)st * D + lane * 4);
        }
        *reinterpret_cast<f32x4*>(out + xb + (size_t)j * D + lane * 4) = v;
    }
}

extern "C" void kernel_launch(void* const* d_in, const int* in_sizes, int n_in,
                              void* d_out, int out_size, void* d_ws, size_t ws_size,
                              hipStream_t stream) {
    const float* x    = (const float*)d_in[0];   // (B, T, D) fp32
    const float* rand = (const float*)d_in[1];   // (B, T)    fp32
    float* out        = (float*)d_out;

    const int BT = in_sizes[1];                  // B*T = 131072
    seqmask_fused_kernel<<<BT / 16, 256, 0, stream>>>(x, rand, out);
}